// Round 1
// baseline (6126.676 us; speedup 1.0000x reference)
//
#include <hip/hip_runtime.h>
#include <math.h>

// ---------------- workspace layout (floats) ----------------
// h1   : [4096][32][16][16]  = 33554432
// h2   : [4096][64][8][8]    = 16777216
// feat : [4096][128]         = 524288
// w1r  : [ci3][k9][o32]      = 864
// w2r  : [q4][ci32][k9][o16] = 18432
// w3r  : [oc4][cc4][ci16][k9][o32] = 73728
// sb1  : scale32|bias32      = 64
// sb2  : scale64|bias64      = 128
// sb3  : scale128|bias128    = 256
// total = 50,949,408 floats = 194.4 MiB
static const size_t H1_OFF   = 0;
static const size_t H1_N     = (size_t)4096*32*16*16;
static const size_t H2_OFF   = H1_OFF + H1_N;
static const size_t H2_N     = (size_t)4096*64*8*8;
static const size_t FEAT_OFF = H2_OFF + H2_N;
static const size_t FEAT_N   = (size_t)4096*128;
static const size_t W1R_OFF  = FEAT_OFF + FEAT_N;
static const size_t W1R_N    = 3*9*32;
static const size_t W2R_OFF  = W1R_OFF + W1R_N;
static const size_t W2R_N    = 4*32*9*16;
static const size_t W3R_OFF  = W2R_OFF + W2R_N;
static const size_t W3R_N    = 4*4*16*9*32;
static const size_t SB1_OFF  = W3R_OFF + W3R_N;
static const size_t SB2_OFF  = SB1_OFF + 64;
static const size_t SB3_OFF  = SB2_OFF + 128;

#define BN_EPS 1e-5f

// ---------------- prep: reorder weights + fold BN ----------------
__global__ __launch_bounds__(256) void k_prep(
    const float* __restrict__ c1w, const float* __restrict__ c2w, const float* __restrict__ c3w,
    const float* __restrict__ c1b, const float* __restrict__ g1, const float* __restrict__ be1,
    const float* __restrict__ m1, const float* __restrict__ v1,
    const float* __restrict__ c2b, const float* __restrict__ g2, const float* __restrict__ be2,
    const float* __restrict__ m2, const float* __restrict__ v2,
    const float* __restrict__ c3b, const float* __restrict__ g3, const float* __restrict__ be3,
    const float* __restrict__ m3, const float* __restrict__ v3,
    float* __restrict__ w1r, float* __restrict__ w2r, float* __restrict__ w3r,
    float* __restrict__ sb1, float* __restrict__ sb2, float* __restrict__ sb3)
{
    int i = blockIdx.x * 256 + threadIdx.x;
    if (i < 864) {                       // w1r [ci][k][o32] <- c1w [o][ci][k]
        int ci = i / 288, k = (i / 32) % 9, o = i & 31;
        w1r[i] = c1w[o*27 + ci*9 + k];
        return;
    }
    i -= 864;
    if (i < 18432) {                     // w2r [q][ci][k][o16] <- c2w [o][ci][k]
        int q = i / 4608, r = i % 4608;
        int ci = r / 144, k = (r / 16) % 9, o = q*16 + (r & 15);
        w2r[i] = c2w[o*288 + ci*9 + k];
        return;
    }
    i -= 18432;
    if (i < 73728) {                     // w3r [oc][cc][ci16][k][o32] <- c3w [o][cig][k]
        int oc = i / 18432, r = i % 18432;
        int cc = r / 4608, r2 = r % 4608;
        int ci = r2 / 288, k = (r2 / 32) % 9, o = oc*32 + (r2 & 31);
        int cig = cc*16 + ci;
        w3r[i] = c3w[o*576 + cig*9 + k];
        return;
    }
    i -= 73728;
    if (i < 32) {
        float s = g1[i] * rsqrtf(v1[i] + BN_EPS);
        sb1[i] = s; sb1[32 + i] = (c1b[i] - m1[i]) * s + be1[i];
        return;
    }
    i -= 32;
    if (i < 64) {
        float s = g2[i] * rsqrtf(v2[i] + BN_EPS);
        sb2[i] = s; sb2[64 + i] = (c2b[i] - m2[i]) * s + be2[i];
        return;
    }
    i -= 64;
    if (i < 128) {
        float s = g3[i] * rsqrtf(v3[i] + BN_EPS);
        sb3[i] = s; sb3[128 + i] = (c3b[i] - m3[i]) * s + be3[i];
        return;
    }
}

// ---------------- conv1: 3->32 @32x32, bn+relu+pool -> h1 [b][32][16][16] ----
__global__ __launch_bounds__(256, 2) void k_conv1(
    const float* __restrict__ x, const float* __restrict__ w1r,
    const float* __restrict__ sb1, float* __restrict__ h1)
{
    __shared__ __align__(16) float sIn[3*34*34];   // 3468
    __shared__ __align__(16) float sW[864];
    __shared__ float sS[32], sB[32];
    const int b = blockIdx.x, t = threadIdx.x;

    for (int i = t; i < 3*34*34; i += 256) sIn[i] = 0.f;
    for (int i = t; i < 864; i += 256) sW[i] = w1r[i];
    if (t < 32) { sS[t] = sb1[t]; sB[t] = sb1[32 + t]; }
    __syncthreads();
    const float* xb = x + (size_t)b * 3*32*32;
    for (int i = t; i < 3*32*32; i += 256) {
        int ci = i >> 10, y = (i >> 5) & 31, xx = i & 31;
        sIn[ci*1156 + (y+1)*34 + (xx+1)] = xb[i];
    }
    __syncthreads();

    const int py = t >> 4, px = t & 15;
    float m[32];
#pragma unroll
    for (int o = 0; o < 32; o++) m[o] = 0.f;     // relu >= 0, safe init

    for (int pos = 0; pos < 4; pos++) {
        const int y = 2*py + (pos >> 1), xx = 2*px + (pos & 1);
        float acc[32];
#pragma unroll
        for (int o = 0; o < 32; o++) acc[o] = 0.f;
        for (int ci = 0; ci < 3; ci++) {
#pragma unroll
            for (int k = 0; k < 9; k++) {
                float a = sIn[ci*1156 + (y + k/3)*34 + (xx + k%3)];
                const float4* wp = (const float4*)&sW[(ci*9 + k)*32];
#pragma unroll
                for (int j = 0; j < 8; j++) {
                    float4 w4 = wp[j];
                    acc[4*j+0] += a*w4.x; acc[4*j+1] += a*w4.y;
                    acc[4*j+2] += a*w4.z; acc[4*j+3] += a*w4.w;
                }
            }
        }
#pragma unroll
        for (int o = 0; o < 32; o++) {
            float v = fmaxf(acc[o]*sS[o] + sB[o], 0.f);
            m[o] = fmaxf(m[o], v);
        }
    }
    float* hb = h1 + (size_t)b * 32*256;
#pragma unroll
    for (int o = 0; o < 32; o++) hb[o*256 + t] = m[o];
}

// ---------------- conv2: 32->64 @16x16, bn+relu+pool -> h2 [b][64][8][8] ----
__global__ __launch_bounds__(256, 2) void k_conv2(
    const float* __restrict__ h1, const float* __restrict__ w2r,
    const float* __restrict__ sb2, float* __restrict__ h2)
{
    __shared__ __align__(16) float sIn[32*18*18];  // 10368 (40.5 KB)
    __shared__ __align__(16) float sW[4608];       // 18 KB
    __shared__ float sS[64], sB[64];
    const int b = blockIdx.x, t = threadIdx.x;

    for (int i = t; i < 32*18*18; i += 256) sIn[i] = 0.f;
    if (t < 64) { sS[t] = sb2[t]; sB[t] = sb2[64 + t]; }
    __syncthreads();
    const float* ib = h1 + (size_t)b * 8192;
    for (int i = t; i < 8192; i += 256) {
        int ci = i >> 8, y = (i >> 4) & 15, xx = i & 15;
        sIn[ci*324 + (y+1)*18 + (xx+1)] = ib[i];
    }

    const int y = t >> 4, xx = t & 15;
    const bool writer = ((y & 1) == 0) && ((xx & 1) == 0);
    const int pp = (y >> 1)*8 + (xx >> 1);
    float* ob = h2 + (size_t)b * 4096;

    for (int q = 0; q < 4; q++) {                  // 16 out channels per pass
        __syncthreads();                           // protect sW (and cover sIn stage at q==0)
        for (int i = t; i < 4608; i += 256) sW[i] = w2r[q*4608 + i];
        __syncthreads();

        float acc[16];
#pragma unroll
        for (int o = 0; o < 16; o++) acc[o] = 0.f;
        for (int ci = 0; ci < 32; ci++) {
#pragma unroll
            for (int k = 0; k < 9; k++) {
                float a = sIn[ci*324 + (y + k/3)*18 + (xx + k%3)];
                const float4* wp = (const float4*)&sW[(ci*9 + k)*16];
#pragma unroll
                for (int j = 0; j < 4; j++) {
                    float4 w4 = wp[j];
                    acc[4*j+0] += a*w4.x; acc[4*j+1] += a*w4.y;
                    acc[4*j+2] += a*w4.z; acc[4*j+3] += a*w4.w;
                }
            }
        }
#pragma unroll
        for (int o = 0; o < 16; o++) {
            int og = q*16 + o;
            float v = fmaxf(acc[o]*sS[og] + sB[og], 0.f);
            v = fmaxf(v, __shfl_xor(v, 1, 64));    // x-pair
            v = fmaxf(v, __shfl_xor(v, 16, 64));   // y-pair
            if (writer) ob[og*64 + pp] = v;
        }
    }
}

// ---------------- conv3: 64->128 @8x8, bn+relu+pool+avg -> feat [b][128] ----
__global__ __launch_bounds__(256, 2) void k_conv3(
    const float* __restrict__ h2, const float* __restrict__ w3r,
    const float* __restrict__ sb3, float* __restrict__ feat)
{
    __shared__ __align__(16) float sIn[64*10*10];  // 6400 (25 KB)
    __shared__ __align__(16) float sW[4608];       // 18 KB
    __shared__ float sS[128], sB[128];
    const int b = blockIdx.x, t = threadIdx.x;

    for (int i = t; i < 6400; i += 256) sIn[i] = 0.f;
    if (t < 128) { sS[t] = sb3[t]; sB[t] = sb3[128 + t]; }
    __syncthreads();
    const float* ib = h2 + (size_t)b * 4096;
    for (int i = t; i < 4096; i += 256) {
        int ci = i >> 6, y = (i >> 3) & 7, xx = i & 7;
        sIn[ci*100 + (y+1)*10 + (xx+1)] = ib[i];
    }

    const int pos = t & 63, og = t >> 6;           // wave og handles o = oc*32 + og*8 + j
    const int y = pos >> 3, xx = pos & 7;
    float* fb = feat + (size_t)b * 128;

    for (int oc = 0; oc < 4; oc++) {
        float acc[8];
#pragma unroll
        for (int j = 0; j < 8; j++) acc[j] = 0.f;
        for (int cc = 0; cc < 4; cc++) {
            __syncthreads();
            const float* wsrc = w3r + (size_t)(oc*4 + cc)*4608;
            for (int i = t; i < 4608; i += 256) sW[i] = wsrc[i];
            __syncthreads();
            for (int ci = 0; ci < 16; ci++) {
                int cig = cc*16 + ci;
#pragma unroll
                for (int k = 0; k < 9; k++) {
                    float a = sIn[cig*100 + (y + k/3)*10 + (xx + k%3)];
                    const float4* wp = (const float4*)&sW[(ci*9 + k)*32 + og*8];
                    float4 wa = wp[0], wb = wp[1];
                    acc[0] += a*wa.x; acc[1] += a*wa.y; acc[2] += a*wa.z; acc[3] += a*wa.w;
                    acc[4] += a*wb.x; acc[5] += a*wb.y; acc[6] += a*wb.z; acc[7] += a*wb.w;
                }
            }
        }
#pragma unroll
        for (int j = 0; j < 8; j++) {
            int o = oc*32 + og*8 + j;
            float v = fmaxf(acc[j]*sS[o] + sB[o], 0.f);
            v = fmaxf(v, __shfl_xor(v, 1, 64));    // 2x2 max-pool
            v = fmaxf(v, __shfl_xor(v, 8, 64));
            float s = v;                            // each group max appears 4x -> /64 = mean/16
            s += __shfl_xor(s, 1, 64);
            s += __shfl_xor(s, 2, 64);
            s += __shfl_xor(s, 4, 64);
            s += __shfl_xor(s, 8, 64);
            s += __shfl_xor(s, 16, 64);
            s += __shfl_xor(s, 32, 64);
            if (pos == 0) fb[o] = s * (1.0f/64.0f);
        }
    }
}

// ---------------- head: gate top-2 + 2 expert MLPs -> out [b][10] ----------
__global__ __launch_bounds__(256) void k_head(
    const float* __restrict__ feat,
    const float* __restrict__ w1, const float* __restrict__ b1,
    const float* __restrict__ w2, const float* __restrict__ b2,
    const float* __restrict__ gw, const float* __restrict__ gb,
    float* __restrict__ out)
{
    const int t = threadIdx.x, lane = t & 63, wv = t >> 6;
    const int b = blockIdx.x*4 + wv;
    const float* fb = feat + (size_t)b * 128;
    float f0 = fb[lane], f1 = fb[64 + lane];

    float lg[8];
#pragma unroll
    for (int e = 0; e < 8; e++) {
        float p = f0*gw[lane*8 + e] + f1*gw[(64 + lane)*8 + e];
#pragma unroll
        for (int s = 1; s < 64; s <<= 1) p += __shfl_xor(p, s, 64);
        lg[e] = p + gb[e];
    }
    float v1 = -INFINITY, v2 = -INFINITY; int i1 = 0, i2 = 0;
#pragma unroll
    for (int e = 0; e < 8; e++) {
        float le = lg[e];
        if (le > v1) { v2 = v1; i2 = i1; v1 = le; i1 = e; }
        else if (le > v2) { v2 = le; i2 = e; }
    }
    float ex = expf(v2 - v1);
    float wk1 = 1.f / (1.f + ex), wk2 = ex / (1.f + ex);

    float o_acc[10];
#pragma unroll
    for (int o = 0; o < 10; o++) o_acc[o] = 0.f;

    for (int s = 0; s < 2; s++) {
        int e = (s == 0) ? i1 : i2;
        float wk = (s == 0) ? wk1 : wk2;
        const float* W1 = w1 + (size_t)e * 128*64;
        float hj = b1[e*64 + lane];
        for (int k = 0; k < 128; k++) hj += fb[k] * W1[k*64 + lane];
        hj = fmaxf(hj, 0.f);
        const float* W2 = w2 + (size_t)e * 640 + lane*10;
#pragma unroll
        for (int o = 0; o < 10; o++) {
            float po = hj * W2[o];
#pragma unroll
            for (int sft = 1; sft < 64; sft <<= 1) po += __shfl_xor(po, sft, 64);
            o_acc[o] += wk * (po + b2[e*10 + o]);
        }
    }
    if (lane == 0) {
        float* ob = out + (size_t)b * 10;
#pragma unroll
        for (int o = 0; o < 10; o++) ob[o] = o_acc[o];
    }
}

extern "C" void kernel_launch(void* const* d_in, const int* in_sizes, int n_in,
                              void* d_out, int out_size, void* d_ws, size_t ws_size,
                              hipStream_t stream)
{
    const float* x   = (const float*)d_in[0];
    const float* c1w = (const float*)d_in[1];
    const float* c1b = (const float*)d_in[2];
    const float* g1  = (const float*)d_in[3];
    const float* be1 = (const float*)d_in[4];
    const float* m1  = (const float*)d_in[5];
    const float* v1  = (const float*)d_in[6];
    const float* c2w = (const float*)d_in[7];
    const float* c2b = (const float*)d_in[8];
    const float* g2  = (const float*)d_in[9];
    const float* be2 = (const float*)d_in[10];
    const float* m2  = (const float*)d_in[11];
    const float* v2  = (const float*)d_in[12];
    const float* c3w = (const float*)d_in[13];
    const float* c3b = (const float*)d_in[14];
    const float* g3  = (const float*)d_in[15];
    const float* be3 = (const float*)d_in[16];
    const float* m3  = (const float*)d_in[17];
    const float* v3  = (const float*)d_in[18];
    const float* w1e = (const float*)d_in[19];
    const float* b1e = (const float*)d_in[20];
    const float* w2e = (const float*)d_in[21];
    const float* b2e = (const float*)d_in[22];
    const float* gw  = (const float*)d_in[23];
    const float* gb  = (const float*)d_in[24];

    float* ws  = (float*)d_ws;
    float* h1   = ws + H1_OFF;
    float* h2   = ws + H2_OFF;
    float* feat = ws + FEAT_OFF;
    float* w1r  = ws + W1R_OFF;
    float* w2r  = ws + W2R_OFF;
    float* w3r  = ws + W3R_OFF;
    float* sb1  = ws + SB1_OFF;
    float* sb2  = ws + SB2_OFF;
    float* sb3  = ws + SB3_OFF;

    k_prep<<<365, 256, 0, stream>>>(c1w, c2w, c3w,
                                    c1b, g1, be1, m1, v1,
                                    c2b, g2, be2, m2, v2,
                                    c3b, g3, be3, m3, v3,
                                    w1r, w2r, w3r, sb1, sb2, sb3);
    k_conv1<<<4096, 256, 0, stream>>>(x, w1r, sb1, h1);
    k_conv2<<<4096, 256, 0, stream>>>(h1, w2r, sb2, h2);
    k_conv3<<<4096, 256, 0, stream>>>(h2, w3r, sb3, feat);
    k_head<<<1024, 256, 0, stream>>>(feat, w1e, b1e, w2e, b2e, gw, gb, (float*)d_out);
}

// Round 2
// 2718.169 us; speedup vs baseline: 2.2540x; 2.2540x over previous
//
#include <hip/hip_runtime.h>
#include <math.h>

// ---------------- workspace layout (floats) ----------------
static const size_t H1_OFF   = 0;
static const size_t H1_N     = (size_t)4096*32*16*16;
static const size_t H2_OFF   = H1_OFF + H1_N;
static const size_t H2_N     = (size_t)4096*64*8*8;
static const size_t FEAT_OFF = H2_OFF + H2_N;
static const size_t FEAT_N   = (size_t)4096*128;
static const size_t W1R_OFF  = FEAT_OFF + FEAT_N;
static const size_t W1R_N    = 3*9*32;
static const size_t W2R_OFF  = W1R_OFF + W1R_N;
static const size_t W2R_N    = 4*32*9*16;
static const size_t W3R_OFF  = W2R_OFF + W2R_N;
static const size_t W3R_N    = 4*4*16*9*32;
static const size_t SB1_OFF  = W3R_OFF + W3R_N;
static const size_t SB2_OFF  = SB1_OFF + 64;
static const size_t SB3_OFF  = SB2_OFF + 128;

#define BN_EPS 1e-5f

// ---------------- prep: reorder weights + fold BN ----------------
__global__ __launch_bounds__(256) void k_prep(
    const float* __restrict__ c1w, const float* __restrict__ c2w, const float* __restrict__ c3w,
    const float* __restrict__ c1b, const float* __restrict__ g1, const float* __restrict__ be1,
    const float* __restrict__ m1, const float* __restrict__ v1,
    const float* __restrict__ c2b, const float* __restrict__ g2, const float* __restrict__ be2,
    const float* __restrict__ m2, const float* __restrict__ v2,
    const float* __restrict__ c3b, const float* __restrict__ g3, const float* __restrict__ be3,
    const float* __restrict__ m3, const float* __restrict__ v3,
    float* __restrict__ w1r, float* __restrict__ w2r, float* __restrict__ w3r,
    float* __restrict__ sb1, float* __restrict__ sb2, float* __restrict__ sb3)
{
    int i = blockIdx.x * 256 + threadIdx.x;
    if (i < 864) {                       // w1r [ci][k][o32] <- c1w [o][ci][k]
        int ci = i / 288, k = (i / 32) % 9, o = i & 31;
        w1r[i] = c1w[o*27 + ci*9 + k];
        return;
    }
    i -= 864;
    if (i < 18432) {                     // w2r [q][ci][k][o16] <- c2w [o][ci][k]
        int q = i / 4608, r = i % 4608;
        int ci = r / 144, k = (r / 16) % 9, o = q*16 + (r & 15);
        w2r[i] = c2w[o*288 + ci*9 + k];
        return;
    }
    i -= 18432;
    if (i < 73728) {                     // w3r [oc][cig64][k][o32] <- c3w [o][cig][k]
        int oc = i / 18432, r = i % 18432;
        int cig = r / 288, k = (r / 32) % 9, o = oc*32 + (r & 31);
        w3r[i] = c3w[o*576 + cig*9 + k];
        return;
    }
    i -= 73728;
    if (i < 32) {
        float s = g1[i] * rsqrtf(v1[i] + BN_EPS);
        sb1[i] = s; sb1[32 + i] = (c1b[i] - m1[i]) * s + be1[i];
        return;
    }
    i -= 32;
    if (i < 64) {
        float s = g2[i] * rsqrtf(v2[i] + BN_EPS);
        sb2[i] = s; sb2[64 + i] = (c2b[i] - m2[i]) * s + be2[i];
        return;
    }
    i -= 64;
    if (i < 128) {
        float s = g3[i] * rsqrtf(v3[i] + BN_EPS);
        sb3[i] = s; sb3[128 + i] = (c3b[i] - m3[i]) * s + be3[i];
        return;
    }
}

// ---------------- conv1: 3->32 @32x32, bn+relu+pool -> h1 [b][32][16][16] ----
// Weights/scales read from global with wave-uniform indices -> s_load (SGPR),
// activations from LDS. 8 output channels per pass: <=40 live VGPRs, no spill.
__global__ __launch_bounds__(256) void k_conv1(
    const float* __restrict__ x, const float* __restrict__ w1r,
    const float* __restrict__ sb1, float* __restrict__ h1)
{
    __shared__ __align__(16) float sIn[3*34*34];   // 13.9 KB
    const int b = blockIdx.x, t = threadIdx.x;

    for (int i = t; i < 3*34*34; i += 256) sIn[i] = 0.f;
    __syncthreads();
    const float* xb = x + (size_t)b * 3072;
    for (int i = t; i < 3072; i += 256) {
        int ci = i >> 10, y = (i >> 5) & 31, xx = i & 31;
        sIn[ci*1156 + (y+1)*34 + (xx+1)] = xb[i];
    }
    __syncthreads();

    const int py = t >> 4, px = t & 15;
    float* hb = h1 + (size_t)b * 8192;

#pragma unroll 1
    for (int oc = 0; oc < 4; oc++) {
        const float* wbase = w1r + oc*8;
        float m8[8];
#pragma unroll
        for (int j = 0; j < 8; j++) m8[j] = 0.f;   // relu >= 0
#pragma unroll
        for (int pos = 0; pos < 4; pos++) {
            const int y = 2*py + (pos >> 1), xx = 2*px + (pos & 1);
            float acc[8];
#pragma unroll
            for (int j = 0; j < 8; j++) acc[j] = 0.f;
#pragma unroll
            for (int ci = 0; ci < 3; ci++) {
#pragma unroll
                for (int k = 0; k < 9; k++) {
                    float a = sIn[ci*1156 + (y + k/3)*34 + (xx + k%3)];
                    const float* wp = wbase + (ci*9 + k)*32;
#pragma unroll
                    for (int j = 0; j < 8; j++) acc[j] += a * wp[j];
                }
            }
#pragma unroll
            for (int j = 0; j < 8; j++) {
                int o = oc*8 + j;
                float v = fmaxf(acc[j]*sb1[o] + sb1[32 + o], 0.f);
                m8[j] = fmaxf(m8[j], v);
            }
        }
#pragma unroll
        for (int j = 0; j < 8; j++) hb[(oc*8 + j)*256 + t] = m8[j];
    }
}

// ---------------- conv2: 32->64 @16x16, bn+relu+pool -> h2 [b][64][8][8] ----
__global__ __launch_bounds__(256) void k_conv2(
    const float* __restrict__ h1, const float* __restrict__ w2r,
    const float* __restrict__ sb2, float* __restrict__ h2)
{
    __shared__ __align__(16) float sIn[32*18*18];  // 40.5 KB
    const int b = blockIdx.x, t = threadIdx.x;

    for (int i = t; i < 32*18*18; i += 256) sIn[i] = 0.f;
    __syncthreads();
    const float* ib = h1 + (size_t)b * 8192;
    for (int i = t; i < 8192; i += 256) {
        int ci = i >> 8, y = (i >> 4) & 15, xx = i & 15;
        sIn[ci*324 + (y+1)*18 + (xx+1)] = ib[i];
    }
    __syncthreads();

    const int y = t >> 4, xx = t & 15;
    const bool writer = ((y & 1) == 0) && ((xx & 1) == 0);
    const int pp = (y >> 1)*8 + (xx >> 1);
    float* ob = h2 + (size_t)b * 4096;

#pragma unroll 1
    for (int q = 0; q < 4; q++) {                  // 16 out channels per pass
        float acc[16];
#pragma unroll
        for (int o = 0; o < 16; o++) acc[o] = 0.f;
#pragma unroll 1
        for (int ci = 0; ci < 32; ci++) {
#pragma unroll
            for (int k = 0; k < 9; k++) {
                float a = sIn[ci*324 + (y + k/3)*18 + (xx + k%3)];
                const float* wp = w2r + q*4608 + (ci*9 + k)*16;
#pragma unroll
                for (int j = 0; j < 16; j++) acc[j] += a * wp[j];
            }
        }
#pragma unroll
        for (int o = 0; o < 16; o++) {
            int og = q*16 + o;
            float v = fmaxf(acc[o]*sb2[og] + sb2[64 + og], 0.f);
            v = fmaxf(v, __shfl_xor(v, 1, 64));    // x-pair
            v = fmaxf(v, __shfl_xor(v, 16, 64));   // y-pair
            if (writer) ob[og*64 + pp] = v;
        }
    }
}

// ---------------- conv3: 64->128 @8x8, bn+relu+pool+avg -> feat [b][128] ----
__global__ __launch_bounds__(256) void k_conv3(
    const float* __restrict__ h2, const float* __restrict__ w3r,
    const float* __restrict__ sb3, float* __restrict__ feat)
{
    __shared__ __align__(16) float sIn[64*10*10];  // 25 KB
    const int b = blockIdx.x, t = threadIdx.x;

    for (int i = t; i < 6400; i += 256) sIn[i] = 0.f;
    __syncthreads();
    const float* ib = h2 + (size_t)b * 4096;
    for (int i = t; i < 4096; i += 256) {
        int ci = i >> 6, y = (i >> 3) & 7, xx = i & 7;
        sIn[ci*100 + (y+1)*10 + (xx+1)] = ib[i];
    }
    __syncthreads();

    const int pos = t & 63, og = t >> 6;           // wave og -> o = oc*32 + og*8 + j
    const int y = pos >> 3, xx = pos & 7;
    float* fb = feat + (size_t)b * 128;

#pragma unroll 1
    for (int oc = 0; oc < 4; oc++) {
        float acc[8];
#pragma unroll
        for (int j = 0; j < 8; j++) acc[j] = 0.f;
#pragma unroll 1
        for (int cig = 0; cig < 64; cig++) {
#pragma unroll
            for (int k = 0; k < 9; k++) {
                float a = sIn[cig*100 + (y + k/3)*10 + (xx + k%3)];
                const float* wp = w3r + (size_t)(oc*64 + cig)*288 + k*32 + og*8;
#pragma unroll
                for (int j = 0; j < 8; j++) acc[j] += a * wp[j];
            }
        }
#pragma unroll
        for (int j = 0; j < 8; j++) {
            int o = oc*32 + og*8 + j;
            float v = fmaxf(acc[j]*sb3[o] + sb3[128 + o], 0.f);
            v = fmaxf(v, __shfl_xor(v, 1, 64));    // 2x2 max-pool
            v = fmaxf(v, __shfl_xor(v, 8, 64));
            float s = v;                            // group max appears 4x -> /64 = mean/16
            s += __shfl_xor(s, 1, 64);
            s += __shfl_xor(s, 2, 64);
            s += __shfl_xor(s, 4, 64);
            s += __shfl_xor(s, 8, 64);
            s += __shfl_xor(s, 16, 64);
            s += __shfl_xor(s, 32, 64);
            if (pos == 0) fb[o] = s * (1.0f/64.0f);
        }
    }
}

// ---------------- head: gate top-2 + 2 expert MLPs -> out [b][10] ----------
__global__ __launch_bounds__(256) void k_head(
    const float* __restrict__ feat,
    const float* __restrict__ w1, const float* __restrict__ b1,
    const float* __restrict__ w2, const float* __restrict__ b2,
    const float* __restrict__ gw, const float* __restrict__ gb,
    float* __restrict__ out)
{
    const int t = threadIdx.x, lane = t & 63, wv = t >> 6;
    const int b = blockIdx.x*4 + wv;
    const float* fb = feat + (size_t)b * 128;
    float f0 = fb[lane], f1 = fb[64 + lane];

    float lg[8];
#pragma unroll
    for (int e = 0; e < 8; e++) {
        float p = f0*gw[lane*8 + e] + f1*gw[(64 + lane)*8 + e];
#pragma unroll
        for (int s = 1; s < 64; s <<= 1) p += __shfl_xor(p, s, 64);
        lg[e] = p + gb[e];
    }
    float v1 = -INFINITY, v2 = -INFINITY; int i1 = 0, i2 = 0;
#pragma unroll
    for (int e = 0; e < 8; e++) {
        float le = lg[e];
        if (le > v1) { v2 = v1; i2 = i1; v1 = le; i1 = e; }
        else if (le > v2) { v2 = le; i2 = e; }
    }
    float ex = expf(v2 - v1);
    float wk1 = 1.f / (1.f + ex), wk2 = ex / (1.f + ex);

    float o_acc[10];
#pragma unroll
    for (int o = 0; o < 10; o++) o_acc[o] = 0.f;

    for (int s = 0; s < 2; s++) {
        int e = (s == 0) ? i1 : i2;
        float wk = (s == 0) ? wk1 : wk2;
        const float* W1 = w1 + (size_t)e * 128*64;
        float hj = b1[e*64 + lane];
#pragma unroll 8
        for (int k = 0; k < 128; k++) hj += fb[k] * W1[k*64 + lane];
        hj = fmaxf(hj, 0.f);
        const float* W2 = w2 + (size_t)e * 640 + lane*10;
#pragma unroll
        for (int o = 0; o < 10; o++) {
            float po = hj * W2[o];
#pragma unroll
            for (int sft = 1; sft < 64; sft <<= 1) po += __shfl_xor(po, sft, 64);
            o_acc[o] += wk * (po + b2[e*10 + o]);
        }
    }
    if (lane == 0) {
        float* ob = out + (size_t)b * 10;
#pragma unroll
        for (int o = 0; o < 10; o++) ob[o] = o_acc[o];
    }
}

extern "C" void kernel_launch(void* const* d_in, const int* in_sizes, int n_in,
                              void* d_out, int out_size, void* d_ws, size_t ws_size,
                              hipStream_t stream)
{
    const float* x   = (const float*)d_in[0];
    const float* c1w = (const float*)d_in[1];
    const float* c1b = (const float*)d_in[2];
    const float* g1  = (const float*)d_in[3];
    const float* be1 = (const float*)d_in[4];
    const float* m1  = (const float*)d_in[5];
    const float* v1  = (const float*)d_in[6];
    const float* c2w = (const float*)d_in[7];
    const float* c2b = (const float*)d_in[8];
    const float* g2  = (const float*)d_in[9];
    const float* be2 = (const float*)d_in[10];
    const float* m2  = (const float*)d_in[11];
    const float* v2  = (const float*)d_in[12];
    const float* c3w = (const float*)d_in[13];
    const float* c3b = (const float*)d_in[14];
    const float* g3  = (const float*)d_in[15];
    const float* be3 = (const float*)d_in[16];
    const float* m3  = (const float*)d_in[17];
    const float* v3  = (const float*)d_in[18];
    const float* w1e = (const float*)d_in[19];
    const float* b1e = (const float*)d_in[20];
    const float* w2e = (const float*)d_in[21];
    const float* b2e = (const float*)d_in[22];
    const float* gw  = (const float*)d_in[23];
    const float* gb  = (const float*)d_in[24];

    float* ws  = (float*)d_ws;
    float* h1   = ws + H1_OFF;
    float* h2   = ws + H2_OFF;
    float* feat = ws + FEAT_OFF;
    float* w1r  = ws + W1R_OFF;
    float* w2r  = ws + W2R_OFF;
    float* w3r  = ws + W3R_OFF;
    float* sb1  = ws + SB1_OFF;
    float* sb2  = ws + SB2_OFF;
    float* sb3  = ws + SB3_OFF;

    k_prep<<<365, 256, 0, stream>>>(c1w, c2w, c3w,
                                    c1b, g1, be1, m1, v1,
                                    c2b, g2, be2, m2, v2,
                                    c3b, g3, be3, m3, v3,
                                    w1r, w2r, w3r, sb1, sb2, sb3);
    k_conv1<<<4096, 256, 0, stream>>>(x, w1r, sb1, h1);
    k_conv2<<<4096, 256, 0, stream>>>(h1, w2r, sb2, h2);
    k_conv3<<<4096, 256, 0, stream>>>(h2, w3r, sb3, feat);
    k_head<<<1024, 256, 0, stream>>>(feat, w1e, b1e, w2e, b2e, gw, gb, (float*)d_out);
}

// Round 3
// 848.914 us; speedup vs baseline: 7.2171x; 3.2019x over previous
//
#include <hip/hip_runtime.h>
#include <math.h>

typedef __attribute__((ext_vector_type(8))) short short8;
typedef __attribute__((ext_vector_type(4))) float f32x4;
#define MFMA __builtin_amdgcn_mfma_f32_16x16x32_bf16

#define BN_EPS 1e-5f

// ---------------- workspace layout (float offsets) ----------------
// w1c2: 2048 u16  -> 1024 f   [n2][ol16][kc4][p2][e8]
// w2c2: 36864 u16 -> 18432 f  [tap9][n4][ol16][kc4][p2][e8]
// w3c2: 147456 u16-> 73728 f  [tap9][s2][nf8][ol16][kc4][p2][e8]
// b1c: 32 f, b2c: 64 f, b3c: 128 f
static const size_t W1C2_OFF = 0;
static const size_t W2C2_OFF = 1024;
static const size_t W3C2_OFF = 19456;
static const size_t B1_OFF   = 93184;
static const size_t B2_OFF   = 93216;
static const size_t B3_OFF   = 93280;

__device__ inline unsigned short rneb(float x) {
    unsigned u = __float_as_uint(x);
    return (unsigned short)((u + 0x7FFFu + ((u >> 16) & 1u)) >> 16);
}
__device__ inline float b2f(unsigned short h) {
    return __uint_as_float(((unsigned)h) << 16);
}

// ---------------- prep: BN-fold + reorder to MFMA B-fragment layout, hi/lo split
__global__ __launch_bounds__(256) void k_prep(
    const float* __restrict__ c1w, const float* __restrict__ c2w, const float* __restrict__ c3w,
    const float* __restrict__ c1b, const float* __restrict__ g1, const float* __restrict__ be1,
    const float* __restrict__ m1, const float* __restrict__ v1,
    const float* __restrict__ c2b, const float* __restrict__ g2, const float* __restrict__ be2,
    const float* __restrict__ m2, const float* __restrict__ v2,
    const float* __restrict__ c3b, const float* __restrict__ g3, const float* __restrict__ be3,
    const float* __restrict__ m3, const float* __restrict__ v3,
    unsigned short* __restrict__ w1c2, unsigned short* __restrict__ w2c2,
    unsigned short* __restrict__ w3c2,
    float* __restrict__ b1c, float* __restrict__ b2c, float* __restrict__ b3c)
{
    int i = blockIdx.x * 256 + threadIdx.x;
    if (i < 2048) {
        int e = i & 7, p = (i >> 3) & 1, kc = (i >> 4) & 3, ol = (i >> 6) & 15, n = i >> 10;
        int o = n * 16 + ol, k = kc * 8 + e;
        float s = g1[o] * rsqrtf(v1[o] + BN_EPS);
        float wv = (k < 27) ? c1w[o * 27 + k] * s : 0.f;
        unsigned short h = rneb(wv);
        w1c2[i] = p ? rneb(wv - b2f(h)) : h;
        return;
    }
    i -= 2048;
    if (i < 36864) {
        int e = i & 7, p = (i >> 3) & 1, kc = (i >> 4) & 3, ol = (i >> 6) & 15;
        int n = (i >> 10) & 3, tap = i >> 12;
        int o = n * 16 + ol, ci = kc * 8 + e;
        float s = g2[o] * rsqrtf(v2[o] + BN_EPS);
        float wv = c2w[o * 288 + ci * 9 + tap] * s;
        unsigned short h = rneb(wv);
        w2c2[i] = p ? rneb(wv - b2f(h)) : h;
        return;
    }
    i -= 36864;
    if (i < 147456) {
        int e = i & 7, p = (i >> 3) & 1, kc = (i >> 4) & 3, ol = (i >> 6) & 15;
        int nf = (i >> 10) & 7, s_ = (i >> 13) & 1, tap = i >> 14;
        int o = nf * 16 + ol, ci = s_ * 32 + kc * 8 + e;
        float sc = g3[o] * rsqrtf(v3[o] + BN_EPS);
        float wv = c3w[o * 576 + ci * 9 + tap] * sc;
        unsigned short h = rneb(wv);
        w3c2[i] = p ? rneb(wv - b2f(h)) : h;
        return;
    }
    i -= 147456;
    if (i < 32) { float s = g1[i]*rsqrtf(v1[i]+BN_EPS); b1c[i] = (c1b[i]-m1[i])*s + be1[i]; return; }
    i -= 32;
    if (i < 64) { float s = g2[i]*rsqrtf(v2[i]+BN_EPS); b2c[i] = (c2b[i]-m2[i])*s + be2[i]; return; }
    i -= 64;
    if (i < 128) { float s = g3[i]*rsqrtf(v3[i]+BN_EPS); b3c[i] = (c3b[i]-m3[i])*s + be3[i]; return; }
}

// ---------------- fully fused: conv1+conv2+conv3+avg+gate+experts, 1 image/block
// LDS regions:
//  R1 (20736 u16): conv2 input [p2][py18][kc4][px18][e8]  (hi plane 0..10367, lo 10368..)
//                  later reused as conv3 input [p2][py10][kc8][px10][e8] (hi 0..6399, lo 6400..)
//  R2 (6936 u16):  conv1 input bf16 hi/lo planes of [3][34][34]
__global__ __launch_bounds__(512, 4) void k_fused(
    const float* __restrict__ x,
    const unsigned short* __restrict__ w1c2,
    const unsigned short* __restrict__ w2c2,
    const unsigned short* __restrict__ w3c2,
    const float* __restrict__ b1c, const float* __restrict__ b2c, const float* __restrict__ b3c,
    const float* __restrict__ w1e, const float* __restrict__ b1e,
    const float* __restrict__ w2e, const float* __restrict__ b2e,
    const float* __restrict__ gw, const float* __restrict__ gb,
    float* __restrict__ out)
{
    __shared__ __align__(16) unsigned short R1[20736];
    __shared__ __align__(16) unsigned short R2[6936];
    __shared__ float sFeatP[4][128];
    __shared__ float sFeat[128];
    __shared__ float sOut[2][10];

    const int b = blockIdx.x, t = threadIdx.x;
    const int lane = t & 63, w = t >> 6;
    const int l15 = lane & 15, lg = lane >> 4;

    // ---------------- P0: zero LDS, stage x (hi/lo bf16, halo'd) ----------------
    for (int i = t; i < 10368; i += 512) ((int*)R1)[i] = 0;
    for (int i = t; i < 3468;  i += 512) ((int*)R2)[i] = 0;
    __syncthreads();
    {
        const float* xb = x + (size_t)b * 3072;
        for (int i = t; i < 3072; i += 512) {
            int ci = i >> 10, y = (i >> 5) & 31, xx = i & 31;
            float v = xb[i];
            unsigned short h = rneb(v), lo = rneb(v - b2f(h));
            int ei = ci * 1156 + (y + 1) * 34 + (xx + 1);
            R2[ei] = h; R2[3468 + ei] = lo;
        }
    }
    __syncthreads();

    // ---------------- P1: conv1 (3->32 @32x32) MFMA, relu+pool -> R1 (conv2 in) --
    {
        short8 b1h[2], b1l[2];
#pragma unroll
        for (int n = 0; n < 2; n++) {
            const short8* bp = (const short8*)(w1c2 + 16 * ((n * 16 + l15) * 4 + lg));
            b1h[n] = bp[0]; b1l[n] = bp[1];
        }
        int aoff[8];
#pragma unroll
        for (int e = 0; e < 8; e++) {
            int k = lg * 8 + e;
            if (k < 27) { int ci = k / 9; int tp = k - ci * 9; int dy = tp / 3, dx = tp - dy * 3;
                          aoff[e] = ci * 1156 + dy * 34 + dx; }
            else aoff[e] = 0;
        }
        float bia[2] = { b1c[l15], b1c[16 + l15] };
#pragma unroll 1
        for (int q = 0; q < 2; q++) {
            int m0 = 8 * w + 4 * q;
            f32x4 acc[4][2];
#pragma unroll
            for (int mi = 0; mi < 4; mi++)
#pragma unroll
                for (int n = 0; n < 2; n++) acc[mi][n] = (f32x4)0.f;
#pragma unroll
            for (int mi = 0; mi < 4; mi++) {
                int pos = 16 * (m0 + mi) + l15, py = pos >> 5, px = pos & 31;
                int base = py * 34 + px;
                short8 ah, al;
#pragma unroll
                for (int e = 0; e < 8; e++) {
                    ah[e] = (short)R2[base + aoff[e]];
                    al[e] = (short)R2[3468 + base + aoff[e]];
                }
#pragma unroll
                for (int n = 0; n < 2; n++) {
                    acc[mi][n] = MFMA(ah, b1h[n], acc[mi][n], 0, 0, 0);
                    acc[mi][n] = MFMA(ah, b1l[n], acc[mi][n], 0, 0, 0);
                    acc[mi][n] = MFMA(al, b1h[n], acc[mi][n], 0, 0, 0);
                }
            }
            int PY = 2 * w + q;
#pragma unroll
            for (int n = 0; n < 2; n++) {
                int o = n * 16 + l15;
#pragma unroll
                for (int h = 0; h < 2; h++)
#pragma unroll
                for (int jp = 0; jp < 2; jp++) {
                    float v00 = fmaxf(acc[h][n][2*jp]     + bia[n], 0.f);
                    float v01 = fmaxf(acc[h][n][2*jp + 1] + bia[n], 0.f);
                    float v10 = fmaxf(acc[h+2][n][2*jp]     + bia[n], 0.f);
                    float v11 = fmaxf(acc[h+2][n][2*jp + 1] + bia[n], 0.f);
                    float pm = fmaxf(fmaxf(v00, v01), fmaxf(v10, v11));
                    int PX = h * 8 + lg * 2 + jp;
                    unsigned short ph = rneb(pm), pl = rneb(pm - b2f(ph));
                    int ei = (((PY + 1) * 4 + (o >> 3)) * 18 + (PX + 1)) * 8 + (o & 7);
                    R1[ei] = ph; R1[10368 + ei] = pl;
                }
            }
        }
    }
    __syncthreads();

    // ---------------- P2: conv2 (32->64 @16x16) MFMA ----------------
    {
        f32x4 acc2[2][4];
#pragma unroll
        for (int mi = 0; mi < 2; mi++)
#pragma unroll
            for (int n = 0; n < 4; n++) acc2[mi][n] = (f32x4)0.f;
#pragma unroll 1
        for (int tap = 0; tap < 9; tap++) {
            int dy = tap / 3, dx = tap - dy * 3;
            short8 b2h[4], b2l[4];
#pragma unroll
            for (int n = 0; n < 4; n++) {
                const short8* bp = (const short8*)(w2c2 + 16 * (((tap * 4 + n) * 16 + l15) * 4 + lg));
                b2h[n] = bp[0]; b2l[n] = bp[1];
            }
#pragma unroll
            for (int mi = 0; mi < 2; mi++) {
                int py = 2 * w + mi;
                int ea = ((py + dy) * 4 + lg) * 144 + (l15 + dx) * 8;
                short8 ah = *(const short8*)(R1 + ea);
                short8 al = *(const short8*)(R1 + 10368 + ea);
#pragma unroll
                for (int n = 0; n < 4; n++) {
                    acc2[mi][n] = MFMA(ah, b2h[n], acc2[mi][n], 0, 0, 0);
                    acc2[mi][n] = MFMA(ah, b2l[n], acc2[mi][n], 0, 0, 0);
                    acc2[mi][n] = MFMA(al, b2h[n], acc2[mi][n], 0, 0, 0);
                }
            }
        }
        __syncthreads();                       // all conv2 reads of R1 done
        for (int i = t; i < 6400; i += 512) ((int*)R1)[i] = 0;   // zero conv3 input
        __syncthreads();
        // epilogue: relu+2x2 maxpool (fully in-lane) -> conv3 input (hi/lo)
#pragma unroll
        for (int n = 0; n < 4; n++) {
            int o = n * 16 + l15;
            float bia = b2c[o];
#pragma unroll
            for (int jp = 0; jp < 2; jp++) {
                float v00 = fmaxf(acc2[0][n][2*jp]     + bia, 0.f);
                float v01 = fmaxf(acc2[0][n][2*jp + 1] + bia, 0.f);
                float v10 = fmaxf(acc2[1][n][2*jp]     + bia, 0.f);
                float v11 = fmaxf(acc2[1][n][2*jp + 1] + bia, 0.f);
                float pm = fmaxf(fmaxf(v00, v01), fmaxf(v10, v11));
                int PX = lg * 2 + jp;
                unsigned short ph = rneb(pm), pl = rneb(pm - b2f(ph));
                int ei = (((w + 1) * 8 + (o >> 3)) * 10 + (PX + 1)) * 8 + (o & 7);
                R1[ei] = ph; R1[6400 + ei] = pl;
            }
        }
    }
    __syncthreads();

    // ---------------- P3: conv3 (64->128 @8x8) MFMA, relu+pool+avg -> sFeat ------
    {
        f32x4 acc3[4];
#pragma unroll
        for (int ni = 0; ni < 4; ni++) acc3[ni] = (f32x4)0.f;
        const int m3 = w & 3, nfg = w >> 2;
        const int py3 = 2 * m3 + ((lane >> 3) & 1), px3 = lane & 7;
#pragma unroll 1
        for (int tap = 0; tap < 9; tap++) {
            int dy = tap / 3, dx = tap - dy * 3;
#pragma unroll
            for (int s = 0; s < 2; s++) {
                int ea = ((py3 + dy) * 8 + s * 4 + lg) * 80 + (px3 + dx) * 8;
                short8 ah = *(const short8*)(R1 + ea);
                short8 al = *(const short8*)(R1 + 6400 + ea);
#pragma unroll
                for (int ni = 0; ni < 4; ni++) {
                    int nf = nfg * 4 + ni;
                    const short8* bp = (const short8*)(w3c2 + 16 * ((((tap * 2 + s) * 8 + nf) * 16 + l15) * 4 + lg));
                    short8 bh = bp[0], bl = bp[1];
                    acc3[ni] = MFMA(ah, bh, acc3[ni], 0, 0, 0);
                    acc3[ni] = MFMA(ah, bl, acc3[ni], 0, 0, 0);
                    acc3[ni] = MFMA(al, bh, acc3[ni], 0, 0, 0);
                }
            }
        }
        // epilogue: relu + 2x2 maxpool + partial avg
#pragma unroll
        for (int ni = 0; ni < 4; ni++) {
            int o = (nfg * 4 + ni) * 16 + l15;
            float bia = b3c[o];
            float sumv = 0.f;
#pragma unroll
            for (int jp = 0; jp < 2; jp++) {
                float v0 = fmaxf(acc3[ni][2*jp]     + bia, 0.f);
                float v1 = fmaxf(acc3[ni][2*jp + 1] + bia, 0.f);
                float vm = fmaxf(v0, v1);
                vm = fmaxf(vm, __shfl_xor(vm, 32, 64));   // py-pair
                sumv += vm;
            }
            sumv += __shfl_xor(sumv, 16, 64);             // combine px-quarters
            if (lane < 16) sFeatP[m3][o] = sumv;
        }
    }
    __syncthreads();
    if (t < 128) sFeat[t] = (sFeatP[0][t] + sFeatP[1][t] + sFeatP[2][t] + sFeatP[3][t]) * (1.0f / 16.0f);
    __syncthreads();

    // ---------------- P4: gate top-2 + 2 expert MLPs ----------------
    if (w < 2) {
        float f0 = sFeat[lane], f1 = sFeat[64 + lane];
        float lgt[8];
#pragma unroll
        for (int e = 0; e < 8; e++) {
            float p = f0 * gw[lane * 8 + e] + f1 * gw[(64 + lane) * 8 + e];
#pragma unroll
            for (int s = 1; s < 64; s <<= 1) p += __shfl_xor(p, s, 64);
            lgt[e] = p + gb[e];
        }
        float v1m = -1e30f, v2m = -1e30f; int i1 = 0, i2 = 0;
#pragma unroll
        for (int e = 0; e < 8; e++) {
            float le = lgt[e];
            if (le > v1m) { v2m = v1m; i2 = i1; v1m = le; i1 = e; }
            else if (le > v2m) { v2m = le; i2 = e; }
        }
        float ex = expf(v2m - v1m);
        float wk = (w == 0) ? 1.f / (1.f + ex) : ex / (1.f + ex);
        int e = (w == 0) ? i1 : i2;
        const float* W1 = w1e + (size_t)e * 8192;
        float hj = b1e[e * 64 + lane];
#pragma unroll 8
        for (int k = 0; k < 128; k++) hj += sFeat[k] * W1[k * 64 + lane];
        hj = fmaxf(hj, 0.f);
        const float* W2 = w2e + (size_t)e * 640 + lane * 10;
#pragma unroll
        for (int o = 0; o < 10; o++) {
            float po = hj * W2[o];
#pragma unroll
            for (int s = 1; s < 64; s <<= 1) po += __shfl_xor(po, s, 64);
            if (lane == 0) sOut[w][o] = wk * (po + b2e[e * 10 + o]);
        }
    }
    __syncthreads();
    if (t < 10) out[(size_t)b * 10 + t] = sOut[0][t] + sOut[1][t];
}

extern "C" void kernel_launch(void* const* d_in, const int* in_sizes, int n_in,
                              void* d_out, int out_size, void* d_ws, size_t ws_size,
                              hipStream_t stream)
{
    const float* x   = (const float*)d_in[0];
    const float* c1w = (const float*)d_in[1];
    const float* c1b = (const float*)d_in[2];
    const float* g1  = (const float*)d_in[3];
    const float* be1 = (const float*)d_in[4];
    const float* m1  = (const float*)d_in[5];
    const float* v1  = (const float*)d_in[6];
    const float* c2w = (const float*)d_in[7];
    const float* c2b = (const float*)d_in[8];
    const float* g2  = (const float*)d_in[9];
    const float* be2 = (const float*)d_in[10];
    const float* m2  = (const float*)d_in[11];
    const float* v2  = (const float*)d_in[12];
    const float* c3w = (const float*)d_in[13];
    const float* c3b = (const float*)d_in[14];
    const float* g3  = (const float*)d_in[15];
    const float* be3 = (const float*)d_in[16];
    const float* m3  = (const float*)d_in[17];
    const float* v3  = (const float*)d_in[18];
    const float* w1e = (const float*)d_in[19];
    const float* b1e = (const float*)d_in[20];
    const float* w2e = (const float*)d_in[21];
    const float* b2e = (const float*)d_in[22];
    const float* gw  = (const float*)d_in[23];
    const float* gb  = (const float*)d_in[24];

    float* ws = (float*)d_ws;
    unsigned short* w1c2 = (unsigned short*)(ws + W1C2_OFF);
    unsigned short* w2c2 = (unsigned short*)(ws + W2C2_OFF);
    unsigned short* w3c2 = (unsigned short*)(ws + W3C2_OFF);
    float* b1c = ws + B1_OFF;
    float* b2c = ws + B2_OFF;
    float* b3c = ws + B3_OFF;

    k_prep<<<729, 256, 0, stream>>>(c1w, c2w, c3w,
                                    c1b, g1, be1, m1, v1,
                                    c2b, g2, be2, m2, v2,
                                    c3b, g3, be3, m3, v3,
                                    w1c2, w2c2, w3c2, b1c, b2c, b3c);
    k_fused<<<4096, 512, 0, stream>>>(x, w1c2, w2c2, w3c2, b1c, b2c, b3c,
                                      w1e, b1e, w2e, b2e, gw, gb, (float*)d_out);
}

// Round 4
// 303.567 us; speedup vs baseline: 20.1823x; 2.7965x over previous
//
#include <hip/hip_runtime.h>
#include <math.h>

typedef __attribute__((ext_vector_type(8))) short short8;
typedef __attribute__((ext_vector_type(4))) float f32x4;
#define MFMA __builtin_amdgcn_mfma_f32_16x16x32_bf16

#define BN_EPS 1e-5f

// ---------------- workspace layout (float offsets) ----------------
// w1c2: 2048 u16   [n2][ol16][kc4][p2][e8]
// w2c2: 36864 u16  [tap9][n4][ol16][kc4][p2][e8]
// w3c2: 147456 u16 [tap9][s2][nf8][ol16][kc4][p2][e8]
static const size_t W1C2_OFF = 0;
static const size_t W2C2_OFF = 1024;
static const size_t W3C2_OFF = 19456;
static const size_t B1_OFF   = 93184;
static const size_t B2_OFF   = 93216;
static const size_t B3_OFF   = 93280;

__device__ inline unsigned short rneb(float x) {
    unsigned u = __float_as_uint(x);
    return (unsigned short)((u + 0x7FFFu + ((u >> 16) & 1u)) >> 16);
}
__device__ inline float b2f(unsigned short h) {
    return __uint_as_float(((unsigned)h) << 16);
}

// ---------------- prep: BN-fold + reorder to MFMA B-fragment layout, hi/lo split
__global__ __launch_bounds__(256) void k_prep(
    const float* __restrict__ c1w, const float* __restrict__ c2w, const float* __restrict__ c3w,
    const float* __restrict__ c1b, const float* __restrict__ g1, const float* __restrict__ be1,
    const float* __restrict__ m1, const float* __restrict__ v1,
    const float* __restrict__ c2b, const float* __restrict__ g2, const float* __restrict__ be2,
    const float* __restrict__ m2, const float* __restrict__ v2,
    const float* __restrict__ c3b, const float* __restrict__ g3, const float* __restrict__ be3,
    const float* __restrict__ m3, const float* __restrict__ v3,
    unsigned short* __restrict__ w1c2, unsigned short* __restrict__ w2c2,
    unsigned short* __restrict__ w3c2,
    float* __restrict__ b1c, float* __restrict__ b2c, float* __restrict__ b3c)
{
    int i = blockIdx.x * 256 + threadIdx.x;
    if (i < 2048) {
        int e = i & 7, p = (i >> 3) & 1, kc = (i >> 4) & 3, ol = (i >> 6) & 15, n = i >> 10;
        int o = n * 16 + ol, k = kc * 8 + e;
        float s = g1[o] * rsqrtf(v1[o] + BN_EPS);
        float wv = (k < 27) ? c1w[o * 27 + k] * s : 0.f;
        unsigned short h = rneb(wv);
        w1c2[i] = p ? rneb(wv - b2f(h)) : h;
        return;
    }
    i -= 2048;
    if (i < 36864) {
        int e = i & 7, p = (i >> 3) & 1, kc = (i >> 4) & 3, ol = (i >> 6) & 15;
        int n = (i >> 10) & 3, tap = i >> 12;
        int o = n * 16 + ol, ci = kc * 8 + e;
        float s = g2[o] * rsqrtf(v2[o] + BN_EPS);
        float wv = c2w[o * 288 + ci * 9 + tap] * s;
        unsigned short h = rneb(wv);
        w2c2[i] = p ? rneb(wv - b2f(h)) : h;
        return;
    }
    i -= 36864;
    if (i < 147456) {
        int e = i & 7, p = (i >> 3) & 1, kc = (i >> 4) & 3, ol = (i >> 6) & 15;
        int nf = (i >> 10) & 7, s_ = (i >> 13) & 1, tap = i >> 14;
        int o = nf * 16 + ol, ci = s_ * 32 + kc * 8 + e;
        float sc = g3[o] * rsqrtf(v3[o] + BN_EPS);
        float wv = c3w[o * 576 + ci * 9 + tap] * sc;
        unsigned short h = rneb(wv);
        w3c2[i] = p ? rneb(wv - b2f(h)) : h;
        return;
    }
    i -= 147456;
    if (i < 32) { float s = g1[i]*rsqrtf(v1[i]+BN_EPS); b1c[i] = (c1b[i]-m1[i])*s + be1[i]; return; }
    i -= 32;
    if (i < 64) { float s = g2[i]*rsqrtf(v2[i]+BN_EPS); b2c[i] = (c2b[i]-m2[i])*s + be2[i]; return; }
    i -= 64;
    if (i < 128) { float s = g3[i]*rsqrtf(v3[i]+BN_EPS); b3c[i] = (c3b[i]-m3[i])*s + be3[i]; return; }
}

// ---------------- fully fused, 1 image/block, 512 thr ----------------
// R1 (20736 u16): conv2 input [py18][kc4][px18][e8], hi 0 / lo +10368
//                 reused as conv3 input [py10][kc8][px11][e8], hi 0 / lo +7040
// R2 (6936 u16):  conv1 input [3][34][34], hi 0 / lo +3468
__global__ __launch_bounds__(512, 4) void k_fused(
    const float* __restrict__ x,
    const unsigned short* __restrict__ w1c2,
    const unsigned short* __restrict__ w2c2,
    const unsigned short* __restrict__ w3c2,
    const float* __restrict__ b1c, const float* __restrict__ b2c, const float* __restrict__ b3c,
    const float* __restrict__ w1e, const float* __restrict__ b1e,
    const float* __restrict__ w2e, const float* __restrict__ b2e,
    const float* __restrict__ gw, const float* __restrict__ gb,
    float* __restrict__ out)
{
    __shared__ __align__(16) unsigned short R1[20736];
    __shared__ __align__(16) unsigned short R2[6936];
    __shared__ float sFeat[128];
    __shared__ float sOut[2][10];

    const int b = blockIdx.x, t = threadIdx.x;
    const int lane = t & 63, w = t >> 6;
    const int l15 = lane & 15, lg = lane >> 4;

    // ---------------- P0: zero LDS, stage x (hi/lo bf16, halo'd) ----------------
    for (int i = t; i < 10368; i += 512) ((int*)R1)[i] = 0;
    for (int i = t; i < 3468;  i += 512) ((int*)R2)[i] = 0;
    __syncthreads();
    {
        const float* xb = x + (size_t)b * 3072;
        for (int i = t; i < 3072; i += 512) {
            int ci = i >> 10, y = (i >> 5) & 31, xx = i & 31;
            float v = xb[i];
            unsigned short h = rneb(v), lo = rneb(v - b2f(h));
            int ei = ci * 1156 + (y + 1) * 34 + (xx + 1);
            R2[ei] = h; R2[3468 + ei] = lo;
        }
    }
    __syncthreads();

    // ---------------- P1: conv1 (3->32 @32x32), relu+pool -> conv2 input --------
    {
        short8 b1h[2], b1l[2];
#pragma unroll
        for (int n = 0; n < 2; n++) {
            const short8* bp = (const short8*)(w1c2 + 16 * ((n * 16 + l15) * 4 + lg));
            b1h[n] = bp[0]; b1l[n] = bp[1];
        }
        int aoff[8];
#pragma unroll
        for (int e = 0; e < 8; e++) {
            int k = lg * 8 + e;
            if (k < 27) { int ci = k / 9; int tp = k - ci * 9; int dy = tp / 3, dx = tp - dy * 3;
                          aoff[e] = ci * 1156 + dy * 34 + dx; }
            else aoff[e] = 0;
        }
        float bia[2] = { b1c[l15], b1c[16 + l15] };
#pragma unroll 1
        for (int q = 0; q < 2; q++) {
            int m0 = 8 * w + 4 * q;
            f32x4 acc[4][2];
#pragma unroll
            for (int mi = 0; mi < 4; mi++)
#pragma unroll
                for (int n = 0; n < 2; n++) acc[mi][n] = (f32x4)0.f;
#pragma unroll
            for (int mi = 0; mi < 4; mi++) {
                int pos = 16 * (m0 + mi) + l15, py = pos >> 5, px = pos & 31;
                int base = py * 34 + px;
                short8 ah, al;
#pragma unroll
                for (int e = 0; e < 8; e++) {
                    ah[e] = (short)R2[base + aoff[e]];
                    al[e] = (short)R2[3468 + base + aoff[e]];
                }
#pragma unroll
                for (int n = 0; n < 2; n++) {
                    acc[mi][n] = MFMA(ah, b1h[n], acc[mi][n], 0, 0, 0);
                    acc[mi][n] = MFMA(ah, b1l[n], acc[mi][n], 0, 0, 0);
                    acc[mi][n] = MFMA(al, b1h[n], acc[mi][n], 0, 0, 0);
                }
            }
            int PY = 2 * w + q;
#pragma unroll
            for (int n = 0; n < 2; n++) {
                int o = n * 16 + l15;
#pragma unroll
                for (int h = 0; h < 2; h++)
#pragma unroll
                for (int jp = 0; jp < 2; jp++) {
                    float v00 = fmaxf(acc[h][n][2*jp]     + bia[n], 0.f);
                    float v01 = fmaxf(acc[h][n][2*jp + 1] + bia[n], 0.f);
                    float v10 = fmaxf(acc[h+2][n][2*jp]     + bia[n], 0.f);
                    float v11 = fmaxf(acc[h+2][n][2*jp + 1] + bia[n], 0.f);
                    float pm = fmaxf(fmaxf(v00, v01), fmaxf(v10, v11));
                    int PX = h * 8 + lg * 2 + jp;
                    unsigned short ph = rneb(pm), pl = rneb(pm - b2f(ph));
                    int ei = (((PY + 1) * 4 + (o >> 3)) * 18 + (PX + 1)) * 8 + (o & 7);
                    R1[ei] = ph; R1[10368 + ei] = pl;
                }
            }
        }
    }
    __syncthreads();

    // ---------------- P2: conv2 (32->64 @16x16), N-split waves + B prefetch -----
    {
        const int mh = w & 1, nn = w >> 1;          // wave: m-half, n-group
        f32x4 acc2[8];
#pragma unroll
        for (int mi = 0; mi < 8; mi++) acc2[mi] = (f32x4)0.f;
        const unsigned short* wb = w2c2 + ((size_t)(nn * 16 + l15) * 4 + lg) * 16;
        const int abase = (mh * 8) * 576 + lg * 144 + l15 * 8;
        short8 bhA, blA, bhB, blB;
#define LDB2(tp, BH, BL) { const short8* bp = (const short8*)(wb + (tp) * 4096); BH = bp[0]; BL = bp[1]; }
#define CMP2(tp, BH, BL) { int dy_ = (tp) / 3, dx_ = (tp) - 3 * dy_; \
        int roff_ = dy_ * 576 + dx_ * 8; \
        _Pragma("unroll") for (int mi = 0; mi < 8; mi++) { \
            int ea_ = abase + mi * 576 + roff_; \
            short8 ah_ = *(const short8*)(R1 + ea_); \
            short8 al_ = *(const short8*)(R1 + 10368 + ea_); \
            acc2[mi] = MFMA(ah_, BH, acc2[mi], 0, 0, 0); \
            acc2[mi] = MFMA(ah_, BL, acc2[mi], 0, 0, 0); \
            acc2[mi] = MFMA(al_, BH, acc2[mi], 0, 0, 0); } }
        LDB2(0, bhA, blA);
#pragma unroll 1
        for (int tp = 0; tp < 8; tp += 2) {
            LDB2(tp + 1, bhB, blB);
            CMP2(tp, bhA, blA);
            LDB2(tp + 2, bhA, blA);
            CMP2(tp + 1, bhB, blB);
        }
        CMP2(8, bhA, blA);
        __syncthreads();                            // conv2 reads of R1 done
        for (int i = t; i < 7040; i += 512) ((int*)R1)[i] = 0;  // zero conv3 input
        __syncthreads();
        // epilogue: relu + 2x2 maxpool -> conv3 input [py10][kc8][px11][e8]
        {
            int o = nn * 16 + l15;
            float bia = b2c[o];
#pragma unroll
            for (int mi2 = 0; mi2 < 4; mi2++) {
                int PY = mh * 4 + mi2;
#pragma unroll
                for (int jp = 0; jp < 2; jp++) {
                    float v00 = fmaxf(acc2[2*mi2][2*jp]     + bia, 0.f);
                    float v01 = fmaxf(acc2[2*mi2][2*jp + 1] + bia, 0.f);
                    float v10 = fmaxf(acc2[2*mi2+1][2*jp]     + bia, 0.f);
                    float v11 = fmaxf(acc2[2*mi2+1][2*jp + 1] + bia, 0.f);
                    float pm = fmaxf(fmaxf(v00, v01), fmaxf(v10, v11));
                    int PX = lg * 2 + jp;
                    unsigned short ph = rneb(pm), pl = rneb(pm - b2f(ph));
                    int ei = (((PY + 1) * 8 + (o >> 3)) * 11 + (PX + 1)) * 8 + (o & 7);
                    R1[ei] = ph; R1[7040 + ei] = pl;
                }
            }
        }
    }
    __syncthreads();

    // ---------------- P3: conv3 (64->128 @8x8), wave-per-nf + B prefetch --------
    {
        const int nf = w;
        f32x4 acc3[4];
#pragma unroll
        for (int mi = 0; mi < 4; mi++) acc3[mi] = (f32x4)0.f;
        const unsigned short* wb3 = w3c2 + ((size_t)(nf * 16 + l15) * 4 + lg) * 16;
        const int py0 = (l15 >> 3), px3 = l15 & 7;
        short8 bhA, blA, bhB, blB;
#define LDB3(ii, BH, BL) { const short8* bp = (const short8*)(wb3 + (ii) * 8192); BH = bp[0]; BL = bp[1]; }
#define CMP3(ii, BH, BL) { int tap_ = (ii) >> 1, s_ = (ii) & 1; \
        int dy_ = tap_ / 3, dx_ = tap_ - 3 * dy_; \
        int roff_ = dy_ * 704 + (s_ * 4 + lg) * 88 + dx_ * 8 + px3 * 8; \
        _Pragma("unroll") for (int mi = 0; mi < 4; mi++) { \
            int ea_ = (mi * 2 + py0) * 704 + roff_; \
            short8 ah_ = *(const short8*)(R1 + ea_); \
            short8 al_ = *(const short8*)(R1 + 7040 + ea_); \
            acc3[mi] = MFMA(ah_, BH, acc3[mi], 0, 0, 0); \
            acc3[mi] = MFMA(ah_, BL, acc3[mi], 0, 0, 0); \
            acc3[mi] = MFMA(al_, BH, acc3[mi], 0, 0, 0); } }
        LDB3(0, bhA, blA);
#pragma unroll 1
        for (int ii = 0; ii < 16; ii += 2) {
            LDB3(ii + 1, bhB, blB);
            CMP3(ii, bhA, blA);
            LDB3(ii + 2, bhA, blA);
            CMP3(ii + 1, bhB, blB);
        }
        LDB3(17, bhB, blB);
        CMP3(16, bhA, blA);
        CMP3(17, bhB, blB);
        // epilogue: relu + 2x2 maxpool + avg -> sFeat (in-wave reduction)
        {
            int o = nf * 16 + l15;
            float bia = b3c[o];
            float featsum = 0.f;
#pragma unroll
            for (int mi = 0; mi < 4; mi++) {
                float sumv = 0.f;
#pragma unroll
                for (int jp = 0; jp < 2; jp++) {
                    float v0 = fmaxf(acc3[mi][2*jp]     + bia, 0.f);
                    float v1 = fmaxf(acc3[mi][2*jp + 1] + bia, 0.f);
                    float vm = fmaxf(v0, v1);
                    vm = fmaxf(vm, __shfl_xor(vm, 32, 64));   // py-pair
                    sumv += vm;
                }
                sumv += __shfl_xor(sumv, 16, 64);             // px halves
                featsum += sumv;
            }
            if (lane < 16) sFeat[nf * 16 + lane] = featsum * (1.0f / 16.0f);
        }
    }
    __syncthreads();

    // ---------------- P4: gate top-2 + 2 expert MLPs ----------------
    if (w < 2) {
        float f0 = sFeat[lane], f1 = sFeat[64 + lane];
        float lgt[8];
#pragma unroll
        for (int e = 0; e < 8; e++) {
            float p = f0 * gw[lane * 8 + e] + f1 * gw[(64 + lane) * 8 + e];
#pragma unroll
            for (int s = 1; s < 64; s <<= 1) p += __shfl_xor(p, s, 64);
            lgt[e] = p + gb[e];
        }
        float v1m = -1e30f, v2m = -1e30f; int i1 = 0, i2 = 0;
#pragma unroll
        for (int e = 0; e < 8; e++) {
            float le = lgt[e];
            if (le > v1m) { v2m = v1m; i2 = i1; v1m = le; i1 = e; }
            else if (le > v2m) { v2m = le; i2 = e; }
        }
        float ex = expf(v2m - v1m);
        float wk = (w == 0) ? 1.f / (1.f + ex) : ex / (1.f + ex);
        int e = (w == 0) ? i1 : i2;
        const float* W1 = w1e + (size_t)e * 8192;
        float hj = b1e[e * 64 + lane];
#pragma unroll 8
        for (int k = 0; k < 128; k++) hj += sFeat[k] * W1[k * 64 + lane];
        hj = fmaxf(hj, 0.f);
        const float* W2 = w2e + (size_t)e * 640 + lane * 10;
#pragma unroll
        for (int o = 0; o < 10; o++) {
            float po = hj * W2[o];
#pragma unroll
            for (int s = 1; s < 64; s <<= 1) po += __shfl_xor(po, s, 64);
            if (lane == 0) sOut[w][o] = wk * (po + b2e[e * 10 + o]);
        }
    }
    __syncthreads();
    if (t < 10) out[(size_t)b * 10 + t] = sOut[0][t] + sOut[1][t];
}

extern "C" void kernel_launch(void* const* d_in, const int* in_sizes, int n_in,
                              void* d_out, int out_size, void* d_ws, size_t ws_size,
                              hipStream_t stream)
{
    const float* x   = (const float*)d_in[0];
    const float* c1w = (const float*)d_in[1];
    const float* c1b = (const float*)d_in[2];
    const float* g1  = (const float*)d_in[3];
    const float* be1 = (const float*)d_in[4];
    const float* m1  = (const float*)d_in[5];
    const float* v1  = (const float*)d_in[6];
    const float* c2w = (const float*)d_in[7];
    const float* c2b = (const float*)d_in[8];
    const float* g2  = (const float*)d_in[9];
    const float* be2 = (const float*)d_in[10];
    const float* m2  = (const float*)d_in[11];
    const float* v2  = (const float*)d_in[12];
    const float* c3w = (const float*)d_in[13];
    const float* c3b = (const float*)d_in[14];
    const float* g3  = (const float*)d_in[15];
    const float* be3 = (const float*)d_in[16];
    const float* m3  = (const float*)d_in[17];
    const float* v3  = (const float*)d_in[18];
    const float* w1e = (const float*)d_in[19];
    const float* b1e = (const float*)d_in[20];
    const float* w2e = (const float*)d_in[21];
    const float* b2e = (const float*)d_in[22];
    const float* gw  = (const float*)d_in[23];
    const float* gb  = (const float*)d_in[24];

    float* ws = (float*)d_ws;
    unsigned short* w1c2 = (unsigned short*)(ws + W1C2_OFF);
    unsigned short* w2c2 = (unsigned short*)(ws + W2C2_OFF);
    unsigned short* w3c2 = (unsigned short*)(ws + W3C2_OFF);
    float* b1c = ws + B1_OFF;
    float* b2c = ws + B2_OFF;
    float* b3c = ws + B3_OFF;

    k_prep<<<729, 256, 0, stream>>>(c1w, c2w, c3w,
                                    c1b, g1, be1, m1, v1,
                                    c2b, g2, be2, m2, v2,
                                    c3b, g3, be3, m3, v3,
                                    w1c2, w2c2, w3c2, b1c, b2c, b3c);
    k_fused<<<4096, 512, 0, stream>>>(x, w1c2, w2c2, w3c2, b1c, b2c, b3c,
                                      w1e, b1e, w2e, b2e, gw, gb, (float*)d_out);
}